// Round 1
// baseline (390.826 us; speedup 1.0000x reference)
//
#include <hip/hip_runtime.h>
#include <hip/hip_bf16.h>

// Problem constants
#define B_    8
#define CIN   128
#define H_    64
#define W_    64
#define COUT  128
#define KH    4
#define KW    4
#define K_    16
#define HO    61
#define WO    61
#define HW_   (HO * WO)          // 3721
#define NPIX  (B_ * HW_)         // 29768
#define KKTOT (CIN * K_)         // 2048 (GEMM K dim, kk = c*16 + k)
#define PIXB  16                 // pixels per block

typedef short bf16x8 __attribute__((ext_vector_type(8)));
typedef float f32x4  __attribute__((ext_vector_type(4)));

// Pre-flip weight (transposed-conv semantics: k' = 15-k) and convert to bf16.
// A[o][c*16 + k] = weight[o][c][15-k]  (row-major [COUT][2048])
__global__ __launch_bounds__(256) void prep_weight(const float* __restrict__ w,
                                                   __hip_bfloat16* __restrict__ A) {
    int idx = blockIdx.x * 256 + threadIdx.x;      // 0 .. 262143
    int o   = idx >> 11;
    int rem = idx & 2047;
    int c   = rem >> 4;
    int k   = rem & 15;
    float v = w[(o << 11) + (c << 4) + (15 - k)];
    A[idx]  = __float2bfloat16(v);
}

// Fused: bilinear gather -> LDS (bf16) -> MFMA GEMM vs pre-flipped weight.
// Block: 16 pixels x 128 couts. 256 threads = (pix = t&15, k-tap = t>>4).
__global__ __launch_bounds__(256) void deform_main(
        const float* __restrict__ inp, const float* __restrict__ off,
        const float* __restrict__ msk, const __hip_bfloat16* __restrict__ A,
        const float* __restrict__ bias, float* __restrict__ out) {

    // 16 rows (pixels) x 2048 kk, bf16, rotate-by-8*pix swizzle -> 64 KB exactly
    __shared__ __align__(16) __hip_bfloat16 Bs[PIXB * KKTOT];

    const int t   = threadIdx.x;
    const int pix = t & 15;
    const int k   = t >> 4;            // tap 0..15

    // ---- pixel identity -------------------------------------------------
    int  pg     = blockIdx.x * PIXB + pix;
    bool pvalid = pg < NPIX;
    int  pc     = pvalid ? pg : 0;
    int  b      = pc / HW_;
    int  r      = pc - b * HW_;        // ho*61 + wo
    int  ho     = r / WO;
    int  wo     = r - ho * WO;

    // ---- per-(pixel, tap) sampling params (computed once) ---------------
    const int ki = k >> 2, kj = k & 3;
    const size_t offb = (size_t)b * (2 * K_ * HW_);
    float dy = off[offb + (size_t)(2 * k)     * HW_ + r];
    float dx = off[offb + (size_t)(2 * k + 1) * HW_ + r];
    float mm = msk[(size_t)b * (K_ * HW_) + (size_t)k * HW_ + r];
    if (!pvalid) mm = 0.0f;

    float y   = dy + (float)(ki + ho);
    float x   = dx + (float)(kj + wo);
    float y0f = floorf(y), x0f = floorf(x);
    float wy  = y - y0f,   wx  = x - x0f;
    int y0 = (int)y0f, x0 = (int)x0f;
    int y1 = y0 + 1,   x1 = x0 + 1;

    float vy0 = (y0 >= 0 && y0 < H_) ? 1.0f : 0.0f;
    float vy1 = (y1 >= 0 && y1 < H_) ? 1.0f : 0.0f;
    float vx0 = (x0 >= 0 && x0 < W_) ? 1.0f : 0.0f;
    float vx1 = (x1 >= 0 && x1 < W_) ? 1.0f : 0.0f;
    int cy0 = min(max(y0, 0), H_ - 1), cy1 = min(max(y1, 0), H_ - 1);
    int cx0 = min(max(x0, 0), W_ - 1), cx1 = min(max(x1, 0), W_ - 1);

    const int o00 = cy0 * W_ + cx0, o01 = cy0 * W_ + cx1;
    const int o10 = cy1 * W_ + cx0, o11 = cy1 * W_ + cx1;
    const float w00 = (1.0f - wy) * (1.0f - wx) * mm * vy0 * vx0;
    const float w01 = (1.0f - wy) * wx          * mm * vy0 * vx1;
    const float w10 = wy          * (1.0f - wx) * mm * vy1 * vx0;
    const float w11 = wy          * wx          * mm * vy1 * vx1;

    // ---- staging loop: 128 channels, 4 gathers each ----------------------
    const float* pin = inp + (size_t)b * (CIN * H_ * W_);
    const int rot = pix << 3;           // swizzle: rotate kk by 8*pix
    __hip_bfloat16* bsrow = &Bs[pix << 11];
    #pragma unroll 4
    for (int c = 0; c < CIN; ++c) {
        const float* p = pin + ((size_t)c << 12);
        float s = w00 * p[o00] + w01 * p[o01] + w10 * p[o10] + w11 * p[o11];
        int kk = (c << 4) + k;
        bsrow[(kk + rot) & (KKTOT - 1)] = __float2bfloat16(s);
    }
    __syncthreads();

    // ---- MFMA phase: wave handles couts [wv*32, wv*32+32) -----------------
    const int lane = t & 63;
    const int wv   = t >> 6;            // 0..3
    const int quad = lane >> 4;         // 0..3
    const int mrow = lane & 15;         // == pix
    const int q8   = quad << 3;

    const __hip_bfloat16* Arow0 = A + ((size_t)(wv * 32 + mrow) << 11);
    const __hip_bfloat16* Arow1 = Arow0 + (16 << 11);
    const __hip_bfloat16* bsb   = &Bs[mrow << 11];
    const int brot = mrow << 3;

    f32x4 acc0 = {0.f, 0.f, 0.f, 0.f};
    f32x4 acc1 = {0.f, 0.f, 0.f, 0.f};

    #pragma unroll 4
    for (int it = 0; it < KKTOT / 32; ++it) {
        int kk0 = it * 32 + q8;
        bf16x8 a0 = *(const bf16x8*)(const void*)(Arow0 + kk0);
        bf16x8 a1 = *(const bf16x8*)(const void*)(Arow1 + kk0);
        bf16x8 bb = *(const bf16x8*)(const void*)(bsb + ((kk0 + brot) & (KKTOT - 1)));
        acc0 = __builtin_amdgcn_mfma_f32_16x16x32_bf16(a0, bb, acc0, 0, 0, 0);
        acc1 = __builtin_amdgcn_mfma_f32_16x16x32_bf16(a1, bb, acc1, 0, 0, 0);
    }

    // ---- epilogue: C/D layout col=lane&15 (pixel), row=quad*4+j (cout) ----
    if (pvalid) {
        size_t outb = (size_t)b * (COUT * HW_) + r;
        #pragma unroll
        for (int j = 0; j < 4; ++j) {
            int o = wv * 32 + quad * 4 + j;
            out[outb + (size_t)o        * HW_] = acc0[j] + bias[o];
            out[outb + (size_t)(o + 16) * HW_] = acc1[j] + bias[o + 16];
        }
    }
}

extern "C" void kernel_launch(void* const* d_in, const int* in_sizes, int n_in,
                              void* d_out, int out_size, void* d_ws, size_t ws_size,
                              hipStream_t stream) {
    const float* inp  = (const float*)d_in[0];
    const float* off  = (const float*)d_in[1];
    const float* msk  = (const float*)d_in[2];
    const float* wgt  = (const float*)d_in[3];
    const float* bias = (const float*)d_in[4];
    float* out = (float*)d_out;

    // d_ws: bf16 pre-flipped weight, 128*2048*2 = 512 KB
    __hip_bfloat16* A = (__hip_bfloat16*)d_ws;

    prep_weight<<<(COUT * KKTOT) / 256, 256, 0, stream>>>(wgt, A);

    int nblk = (NPIX + PIXB - 1) / PIXB;   // 1861
    deform_main<<<nblk, 256, 0, stream>>>(inp, off, msk, A, bias, out);
}

// Round 2
// 314.862 us; speedup vs baseline: 1.2413x; 1.2413x over previous
//
#include <hip/hip_runtime.h>
#include <hip/hip_bf16.h>

// Problem constants
#define B_    8
#define CIN   128
#define H_    64
#define W_    64
#define COUT  128
#define K_    16
#define HO    61
#define WO    61
#define HW_   (HO * WO)          // 3721
#define NPIX  (B_ * HW_)         // 29768
#define KKTOT (CIN * K_)         // 2048 (GEMM K dim, kk = c*16 + k)
#define KKH   1024               // half of kk staged per phase (32 KB LDS)
#define PIXB  16                 // pixels per block

typedef short bf16x8 __attribute__((ext_vector_type(8)));
typedef float f32x4  __attribute__((ext_vector_type(4)));
typedef float f32x2u __attribute__((ext_vector_type(2), aligned(4)));

// Pre-flip weight (transposed-conv semantics: k' = 15-k) and convert to bf16.
// A[o][c*16 + k] = weight[o][c][15-k]  (row-major [COUT][2048])
__global__ __launch_bounds__(256) void prep_weight(const float* __restrict__ w,
                                                   __hip_bfloat16* __restrict__ A) {
    int idx = blockIdx.x * 256 + threadIdx.x;      // 0 .. 262143
    int o   = idx >> 11;
    int rem = idx & 2047;
    int c   = rem >> 4;
    int k   = rem & 15;
    float v = w[(o << 11) + (c << 4) + (15 - k)];
    A[idx]  = __float2bfloat16(v);
}

// Fused: bilinear gather (float2 row-pairs) -> LDS bf16 -> MFMA GEMM.
// Block: 16 pixels x 128 couts. 256 threads = (pix = t&15, k-tap = t>>4).
// kk split into two 1024 halves to keep LDS at 32 KB (5 blocks/CU).
__global__ __launch_bounds__(256, 5) void deform_main(
        const float* __restrict__ inp, const float* __restrict__ off,
        const float* __restrict__ msk, const __hip_bfloat16* __restrict__ A,
        const float* __restrict__ bias, float* __restrict__ out) {

    // 16 rows (pixels) x 1024 kk, bf16, rotate-by-8*pix swizzle -> 32 KB
    __shared__ __align__(16) __hip_bfloat16 Bs[PIXB * KKH];

    const int t   = threadIdx.x;
    const int pix = t & 15;
    const int k   = t >> 4;            // tap 0..15

    // ---- pixel identity -------------------------------------------------
    int  pg     = blockIdx.x * PIXB + pix;
    bool pvalid = pg < NPIX;
    int  pc     = pvalid ? pg : 0;
    int  b      = pc / HW_;
    int  r      = pc - b * HW_;        // ho*61 + wo
    int  ho     = r / WO;
    int  wo     = r - ho * WO;

    // ---- per-(pixel, tap) sampling params (computed once) ---------------
    const int ki = k >> 2, kj = k & 3;
    const size_t offb = (size_t)b * (2 * K_ * HW_);
    float dy = off[offb + (size_t)(2 * k)     * HW_ + r];
    float dx = off[offb + (size_t)(2 * k + 1) * HW_ + r];
    float mm = msk[(size_t)b * (K_ * HW_) + (size_t)k * HW_ + r];
    if (!pvalid) mm = 0.0f;

    float y   = dy + (float)(ki + ho);
    float x   = dx + (float)(kj + wo);
    float y0f = floorf(y), x0f = floorf(x);
    float wy  = y - y0f,   wx  = x - x0f;
    int y0 = (int)y0f, x0 = (int)x0f;
    int y1 = y0 + 1,   x1 = x0 + 1;

    // y rows: clamp address, fold validity*mask into row weights
    float wy0v = (1.0f - wy) * ((y0 >= 0 && y0 < H_) ? mm : 0.0f);
    float wy1v = wy          * ((y1 >= 0 && y1 < H_) ? mm : 0.0f);
    int cy0 = min(max(y0, 0), H_ - 1), cy1 = min(max(y1, 0), H_ - 1);

    // x pair: one float2 at xb = clamp(x0,0,62); remap weights per x0-xb
    float wx0v = (1.0f - wx) * ((x0 >= 0 && x0 < W_) ? 1.0f : 0.0f);
    float wx1v = wx          * ((x1 >= 0 && x1 < W_) ? 1.0f : 0.0f);
    int xb = min(max(x0, 0), W_ - 2);
    int t0 = x0 - xb;                 // -1, 0, or 1 (else both weights 0)
    float a0 = (t0 == 0) ? wx0v : ((t0 == -1) ? wx1v : 0.0f);
    float a1 = (t0 == 0) ? wx1v : ((t0 ==  1) ? wx0v : 0.0f);

    const float b00 = wy0v * a0, b01 = wy0v * a1;
    const float b10 = wy1v * a0, b11 = wy1v * a1;

    const int ad0 = cy0 * W_ + xb;
    const int ad1 = cy1 * W_ + xb;

    const float* pin = inp + (size_t)b * (CIN * H_ * W_);
    const int rot = pix << 3;          // swizzle: rotate kk by 8*pix
    __hip_bfloat16* bsrow = &Bs[pix << 10];

    // MFMA lane identity
    const int lane = t & 63;
    const int wv   = t >> 6;           // 0..3
    const int quad = lane >> 4;        // 0..3
    const int mrow = lane & 15;        // == pix
    const int q8   = quad << 3;

    const __hip_bfloat16* Arow0 = A + ((size_t)(wv * 32 + mrow) << 11);
    const __hip_bfloat16* Arow1 = Arow0 + (16 << 11);
    const __hip_bfloat16* bsb   = &Bs[mrow << 10];
    const int brot = mrow << 3;

    f32x4 acc0 = {0.f, 0.f, 0.f, 0.f};
    f32x4 acc1 = {0.f, 0.f, 0.f, 0.f};

    #pragma unroll
    for (int half = 0; half < 2; ++half) {
        if (half) __syncthreads();     // previous MFMA reads done before restage

        // ---- stage 64 channels: 2 float2 gathers each -------------------
        const float* pch = pin + ((size_t)(half * 64) << 12);
        #pragma unroll 8
        for (int cc = 0; cc < 64; ++cc) {
            f32x2u f0 = *(const f32x2u*)(const void*)(pch + ad0);
            f32x2u f1 = *(const f32x2u*)(const void*)(pch + ad1);
            float s = b00 * f0[0] + b01 * f0[1] + b10 * f1[0] + b11 * f1[1];
            int kkl = (cc << 4) + k;
            bsrow[(kkl + rot) & (KKH - 1)] = __float2bfloat16(s);
            pch += (size_t)H_ * W_;
        }
        __syncthreads();

        // ---- MFMA over this half's 1024 kk ------------------------------
        const __hip_bfloat16* A0 = Arow0 + half * KKH;
        const __hip_bfloat16* A1 = Arow1 + half * KKH;
        #pragma unroll 4
        for (int it = 0; it < KKH / 32; ++it) {
            int kk0 = it * 32 + q8;
            bf16x8 av0 = *(const bf16x8*)(const void*)(A0 + kk0);
            bf16x8 av1 = *(const bf16x8*)(const void*)(A1 + kk0);
            bf16x8 bb  = *(const bf16x8*)(const void*)(bsb + ((kk0 + brot) & (KKH - 1)));
            acc0 = __builtin_amdgcn_mfma_f32_16x16x32_bf16(av0, bb, acc0, 0, 0, 0);
            acc1 = __builtin_amdgcn_mfma_f32_16x16x32_bf16(av1, bb, acc1, 0, 0, 0);
        }
    }

    // ---- epilogue: C/D layout col=lane&15 (pixel), row=quad*4+j (cout) ----
    if (pvalid) {
        size_t outb = (size_t)b * (COUT * HW_) + r;
        #pragma unroll
        for (int j = 0; j < 4; ++j) {
            int o = wv * 32 + quad * 4 + j;
            out[outb + (size_t)o        * HW_] = acc0[j] + bias[o];
            out[outb + (size_t)(o + 16) * HW_] = acc1[j] + bias[o + 16];
        }
    }
}

extern "C" void kernel_launch(void* const* d_in, const int* in_sizes, int n_in,
                              void* d_out, int out_size, void* d_ws, size_t ws_size,
                              hipStream_t stream) {
    const float* inp  = (const float*)d_in[0];
    const float* off  = (const float*)d_in[1];
    const float* msk  = (const float*)d_in[2];
    const float* wgt  = (const float*)d_in[3];
    const float* bias = (const float*)d_in[4];
    float* out = (float*)d_out;

    // d_ws: bf16 pre-flipped weight, 128*2048*2 = 512 KB
    __hip_bfloat16* A = (__hip_bfloat16*)d_ws;

    prep_weight<<<(COUT * KKTOT) / 256, 256, 0, stream>>>(wgt, A);

    int nblk = (NPIX + PIXB - 1) / PIXB;   // 1861
    deform_main<<<nblk, 256, 0, stream>>>(inp, off, msk, A, bias, out);
}

// Round 3
// 258.886 us; speedup vs baseline: 1.5096x; 1.2162x over previous
//
#include <hip/hip_runtime.h>
#include <hip/hip_bf16.h>
#include <stdint.h>

// Problem constants
#define B_    8
#define CIN   128
#define H_    64
#define W_    64
#define COUT  128
#define K_    16
#define HO    61
#define WO    61
#define HW_   (HO * WO)          // 3721
#define KKTOT (CIN * K_)         // 2048
#define KKH   1024               // kk half staged per phase (32 KB Bs)
#define PIXB  16                 // pixels per block (one row segment)
#define TH    16                 // tile rows
#define TW    32                 // tile cols
#define TCH   16                 // channels per tile group
#define TILE_F (TCH * TH * TW)   // 8192 floats = 32 KB

typedef short bf16x8 __attribute__((ext_vector_type(8)));
typedef float f32x4  __attribute__((ext_vector_type(4)));
typedef float f32x2u __attribute__((ext_vector_type(2), aligned(4)));

// async global->LDS, 16B per lane. LDS dest is wave-uniform base + lane*16.
__device__ __forceinline__ void async_cp16(const float* g, float* l) {
    __builtin_amdgcn_global_load_lds(
        (const __attribute__((address_space(1))) unsigned int*)g,
        (__attribute__((address_space(3))) unsigned int*)l,
        16, 0, 0);
}

// Pre-flip weight (transposed-conv: k' = 15-k), bf16.  A[o][c*16+k] = w[o][c][15-k]
__global__ __launch_bounds__(256) void prep_weight(const float* __restrict__ w,
                                                   __hip_bfloat16* __restrict__ A) {
    int idx = blockIdx.x * 256 + threadIdx.x;
    int o   = idx >> 11;
    int rem = idx & 2047;
    int c   = rem >> 4;
    int k   = rem & 15;
    A[idx]  = __float2bfloat16(w[(o << 11) + (c << 4) + (15 - k)]);
}

// Block = 16 pixels of one (b, ho) row segment x 128 couts. 256 thr = (pix, tap).
// Input window [16 rows x 32 cols] per channel staged to LDS (global_load_lds),
// bilinear gather runs from LDS. Rare out-of-window samples: global fallback.
__global__ __launch_bounds__(256, 2) void deform_main(
        const float* __restrict__ inp, const float* __restrict__ off,
        const float* __restrict__ msk, const __hip_bfloat16* __restrict__ A,
        const float* __restrict__ bias, float* __restrict__ out) {

    __shared__ __align__(16) __hip_bfloat16 Bs[PIXB * KKH];   // 32 KB
    __shared__ __align__(16) float tile[TILE_F];              // 32 KB

    const int t   = threadIdx.x;
    const int pix = t & 15;
    const int k   = t >> 4;            // tap 0..15

    // ---- block decode: bid&7 = batch -> one batch per XCD (L2 locality) ----
    const int bid = blockIdx.x;
    const int b   = bid & 7;
    const int g   = bid >> 3;          // 0..243
    const int ho  = g >> 2;
    const int wt  = (g & 3) << 4;      // col-tile base: 0,16,32,48
    const int wo  = wt + pix;
    const bool pvalid = (wo < WO);
    const int wo_c = pvalid ? wo : (WO - 1);
    const int r    = ho * WO + wo_c;

    // ---- tile window ----
    const int ry_lo = min(max(ho - 5, 0), H_ - TH);   // [0,48]
    const int cx_lo = min(max(wt - 8, 0), W_ - TW);   // {0,8,24,32}, 4-aligned

    // ---- per-(pixel,tap) sampling params ----
    const int ki = k >> 2, kj = k & 3;
    const size_t offb = (size_t)b * (2 * K_ * HW_);
    float dy = off[offb + (size_t)(2 * k)     * HW_ + r];
    float dx = off[offb + (size_t)(2 * k + 1) * HW_ + r];
    float mm = msk[(size_t)b * (K_ * HW_) + (size_t)k * HW_ + r];
    if (!pvalid) mm = 0.0f;

    float y   = dy + (float)(ki + ho);
    float x   = dx + (float)(kj + wo_c);
    float y0f = floorf(y), x0f = floorf(x);
    float wy  = y - y0f,   wx  = x - x0f;
    int y0 = (int)y0f, x0 = (int)x0f;
    int y1 = y0 + 1,   x1 = x0 + 1;

    float wy0v = (1.0f - wy) * ((y0 >= 0 && y0 < H_) ? mm : 0.0f);
    float wy1v = wy          * ((y1 >= 0 && y1 < H_) ? mm : 0.0f);
    int cy0 = min(max(y0, 0), H_ - 1), cy1 = min(max(y1, 0), H_ - 1);

    float wx0v = (1.0f - wx) * ((x0 >= 0 && x0 < W_) ? 1.0f : 0.0f);
    float wx1v = wx          * ((x1 >= 0 && x1 < W_) ? 1.0f : 0.0f);
    int xb = min(max(x0, 0), W_ - 2);
    int tsh = x0 - xb;                 // -1,0,1 (else both x-weights are 0)
    float a0 = (tsh == 0) ? wx0v : ((tsh == -1) ? wx1v : 0.0f);
    float a1 = (tsh == 0) ? wx1v : ((tsh ==  1) ? wx0v : 0.0f);

    const float b00 = wy0v * a0, b01 = wy0v * a1;
    const float b10 = wy1v * a0, b11 = wy1v * a1;
    const int ad0 = cy0 * W_ + xb;     // global fallback addrs
    const int ad1 = cy1 * W_ + xb;

    // tile coords + in-window test
    int t0 = cy0 - ry_lo, t1 = cy1 - ry_lo, u = xb - cx_lo;
    const bool intile = (t0 >= 0) & (t0 < TH) & (t1 >= 0) & (t1 < TH) &
                        (u >= 0) & (u <= TW - 2);
    const float l00 = intile ? b00 : 0.0f, l01 = intile ? b01 : 0.0f;
    const float l10 = intile ? b10 : 0.0f, l11 = intile ? b11 : 0.0f;
    const int tc0 = min(max(t0, 0), TH - 1) * TW + min(max(u, 0), TW - 2);
    const int tc1 = min(max(t1, 0), TH - 1) * TW + min(max(u, 0), TW - 2);

    const float* pin = inp + (size_t)b * (CIN * H_ * W_);

    // staging copy geometry: chunk C = j*256 + t (16B each), 2048 chunks/group
    int sp_off[8];
    float* sl_ptr[8];
    #pragma unroll
    for (int j = 0; j < 8; ++j) {
        int C    = j * 256 + t;
        int chl  = C >> 7;             // channel within group
        int rem  = C & 127;
        int row  = rem >> 3;
        int cc   = rem & 7;
        sp_off[j] = (chl << 12) + (ry_lo + row) * W_ + cx_lo + (cc << 2);
        sl_ptr[j] = tile + (C << 2);
    }

    const int rot = pix << 3;
    __hip_bfloat16* bsrow = &Bs[pix << 10];

    // MFMA identity
    const int lane = t & 63;
    const int wv   = t >> 6;
    const int quad = lane >> 4;
    const int mrow = lane & 15;
    const int q8   = quad << 3;
    const __hip_bfloat16* Arow0 = A + ((size_t)(wv * 32 + mrow) << 11);
    const __hip_bfloat16* Arow1 = Arow0 + (16 << 11);
    const __hip_bfloat16* bsb   = &Bs[mrow << 10];
    const int brot = mrow << 3;

    f32x4 acc0 = {0.f, 0.f, 0.f, 0.f};
    f32x4 acc1 = {0.f, 0.f, 0.f, 0.f};

    #pragma unroll
    for (int half = 0; half < 2; ++half) {
        for (int g4 = 0; g4 < 4; ++g4) {
            const int gch = half * 64 + g4 * 16;
            const float* gbase = pin + ((size_t)gch << 12);
            #pragma unroll
            for (int j = 0; j < 8; ++j)
                async_cp16(gbase + sp_off[j], sl_ptr[j]);
            __syncthreads();           // drains vmcnt -> tile ready

            const float* t0p = tile + tc0;
            const float* t1p = tile + tc1;
            #pragma unroll 8
            for (int cc16 = 0; cc16 < 16; ++cc16) {
                f32x2u f0 = *(const f32x2u*)(t0p + cc16 * (TH * TW));
                f32x2u f1 = *(const f32x2u*)(t1p + cc16 * (TH * TW));
                float s = l00 * f0[0] + l01 * f0[1] + l10 * f1[0] + l11 * f1[1];
                if (!intile) {          // ~never (>=5 sigma); exec-skipped
                    const float* p = pin + ((size_t)(gch + cc16) << 12);
                    f32x2u h0 = *(const f32x2u*)(p + ad0);
                    f32x2u h1 = *(const f32x2u*)(p + ad1);
                    s += b00 * h0[0] + b01 * h0[1] + b10 * h1[0] + b11 * h1[1];
                }
                int kkl = ((g4 * 16 + cc16) << 4) + k;
                bsrow[(kkl + rot) & (KKH - 1)] = __float2bfloat16(s);
            }
            __syncthreads();           // Bs region + tile consumption done
        }

        // ---- MFMA over this half's 1024 kk ----
        const __hip_bfloat16* A0 = Arow0 + half * KKH;
        const __hip_bfloat16* A1 = Arow1 + half * KKH;
        #pragma unroll 4
        for (int it = 0; it < KKH / 32; ++it) {
            int kk0 = it * 32 + q8;
            bf16x8 av0 = *(const bf16x8*)(const void*)(A0 + kk0);
            bf16x8 av1 = *(const bf16x8*)(const void*)(A1 + kk0);
            bf16x8 bb  = *(const bf16x8*)(const void*)(bsb + ((kk0 + brot) & (KKH - 1)));
            acc0 = __builtin_amdgcn_mfma_f32_16x16x32_bf16(av0, bb, acc0, 0, 0, 0);
            acc1 = __builtin_amdgcn_mfma_f32_16x16x32_bf16(av1, bb, acc1, 0, 0, 0);
        }
    }

    // ---- epilogue: C/D col=lane&15 (pixel), row=quad*4+j (cout) ----
    if (pvalid) {
        size_t outb = (size_t)b * (COUT * HW_) + r;
        #pragma unroll
        for (int j = 0; j < 4; ++j) {
            int o = wv * 32 + quad * 4 + j;
            out[outb + (size_t)o        * HW_] = acc0[j] + bias[o];
            out[outb + (size_t)(o + 16) * HW_] = acc1[j] + bias[o + 16];
        }
    }
}

extern "C" void kernel_launch(void* const* d_in, const int* in_sizes, int n_in,
                              void* d_out, int out_size, void* d_ws, size_t ws_size,
                              hipStream_t stream) {
    const float* inp  = (const float*)d_in[0];
    const float* off  = (const float*)d_in[1];
    const float* msk  = (const float*)d_in[2];
    const float* wgt  = (const float*)d_in[3];
    const float* bias = (const float*)d_in[4];
    float* out = (float*)d_out;

    __hip_bfloat16* A = (__hip_bfloat16*)d_ws;   // 512 KB

    prep_weight<<<(COUT * KKTOT) / 256, 256, 0, stream>>>(wgt, A);

    int nblk = B_ * HO * 4;            // 8*61*4 = 1952 (bid&7 = batch)
    deform_main<<<nblk, 256, 0, stream>>>(inp, off, msk, A, bias, out);
}

// Round 4
// 218.505 us; speedup vs baseline: 1.7886x; 1.1848x over previous
//
#include <hip/hip_runtime.h>
#include <hip/hip_bf16.h>

// Problem constants
#define B_    8
#define CIN   128
#define H_    64
#define W_    64
#define COUT  128
#define K_    16
#define HO    61
#define WO    61
#define HW_   (HO * WO)          // 3721
#define KKTOT (CIN * K_)         // 2048
#define KKQ   512                // kk per quarter (Bs = 16 KB)
#define TILW  33                 // padded tile row stride (dwords) -> banks rotate
#define TILCH 8                  // channels per tile group
#define TILSZ (TILCH * 16 * TILW) // 4224 floats = 16.9 KB

typedef short bf16x8 __attribute__((ext_vector_type(8)));
typedef float f32x4  __attribute__((ext_vector_type(4)));
typedef float f32x2u __attribute__((ext_vector_type(2), aligned(4)));
typedef float f32x4u __attribute__((ext_vector_type(4), aligned(4)));

// Pre-flip weight (transposed-conv: k' = 15-k), bf16.  A[o][c*16+k] = w[o][c][15-k]
__global__ __launch_bounds__(256) void prep_weight(const float* __restrict__ w,
                                                   __hip_bfloat16* __restrict__ A) {
    int idx = blockIdx.x * 256 + threadIdx.x;
    int o   = idx >> 11;
    int rem = idx & 2047;
    int c   = rem >> 4;
    int k   = rem & 15;
    A[idx]  = __float2bfloat16(w[(o << 11) + (c << 4) + (15 - k)]);
}

// Block = 16 pixels of one (b,ho) row segment x 128 couts. 256 thr = (pix, tap).
// Padded LDS tile (stride 33) per 8-channel group, staged via coalesced
// global->VGPR->ds_write with register prefetch; gather from LDS; Bs quarter
// (512 kk) shared to MFMA. 33.3 KB LDS -> 4 blocks/CU.
__global__ __launch_bounds__(256, 4) void deform_main(
        const float* __restrict__ inp, const float* __restrict__ off,
        const float* __restrict__ msk, const __hip_bfloat16* __restrict__ A,
        const float* __restrict__ bias, float* __restrict__ out) {

    __shared__ __align__(16) __hip_bfloat16 Bs[16 * KKQ];   // 16 KB
    __shared__ __align__(16) float tile[TILSZ];             // 16.9 KB

    const int t   = threadIdx.x;
    const int pix = t & 15;
    const int k   = t >> 4;            // tap 0..15

    // ---- block decode: bid&7 = batch (XCD/L2 pinning) ----
    const int bid = blockIdx.x;
    const int b   = bid & 7;
    const int g   = bid >> 3;
    const int ho  = g >> 2;
    const int wt  = (g & 3) << 4;
    const int wo  = wt + pix;
    const bool pvalid = (wo < WO);
    const int wo_c = pvalid ? wo : (WO - 1);
    const int r    = ho * WO + wo_c;

    // ---- window: 16 rows x 32 cols, margin ~6 sigma; cx 4-aligned ----
    const int ry_lo = min(max(ho - 6, 0), H_ - 16);
    const int cx_lo = min(max(wt - 6, 0), W_ - 32) & ~3;

    // ---- per-(pixel,tap) sampling params ----
    const int ki = k >> 2, kj = k & 3;
    const size_t offb = (size_t)b * (2 * K_ * HW_);
    float dy = off[offb + (size_t)(2 * k)     * HW_ + r];
    float dx = off[offb + (size_t)(2 * k + 1) * HW_ + r];
    float mm = msk[(size_t)b * (K_ * HW_) + (size_t)k * HW_ + r];
    if (!pvalid) mm = 0.0f;

    float y   = dy + (float)(ki + ho);
    float x   = dx + (float)(kj + wo_c);
    float y0f = floorf(y), x0f = floorf(x);
    float wy  = y - y0f,   wx  = x - x0f;
    int y0 = (int)y0f, x0 = (int)x0f;
    int y1 = y0 + 1,   x1 = x0 + 1;

    float wy0v = (1.0f - wy) * ((y0 >= 0 && y0 < H_) ? mm : 0.0f);
    float wy1v = wy          * ((y1 >= 0 && y1 < H_) ? mm : 0.0f);
    int cy0 = min(max(y0, 0), H_ - 1), cy1 = min(max(y1, 0), H_ - 1);

    float wx0v = (1.0f - wx) * ((x0 >= 0 && x0 < W_) ? 1.0f : 0.0f);
    float wx1v = wx          * ((x1 >= 0 && x1 < W_) ? 1.0f : 0.0f);
    int xb = min(max(x0, 0), W_ - 2);
    int tsh = x0 - xb;                 // -1,0,1 (else both x-weights are 0)
    float a0 = (tsh == 0) ? wx0v : ((tsh == -1) ? wx1v : 0.0f);
    float a1 = (tsh == 0) ? wx1v : ((tsh ==  1) ? wx0v : 0.0f);

    const float b00 = wy0v * a0, b01 = wy0v * a1;
    const float b10 = wy1v * a0, b11 = wy1v * a1;
    const int ad0 = cy0 * W_ + xb;     // exact global fallback addrs
    const int ad1 = cy1 * W_ + xb;

    // tile coords + in-window test (fallback handles the ~6-sigma tail exactly)
    int t0 = cy0 - ry_lo, t1 = cy1 - ry_lo, u = xb - cx_lo;
    const bool intile = (t0 >= 0) & (t0 < 16) & (t1 >= 0) & (t1 < 16) &
                        (u >= 0) & (u <= 30);
    const float l00 = intile ? b00 : 0.0f, l01 = intile ? b01 : 0.0f;
    const float l10 = intile ? b10 : 0.0f, l11 = intile ? b11 : 0.0f;
    const int tc0 = min(max(t0, 0), 15) * TILW + min(max(u, 0), 30);
    const int tc1 = min(max(t1, 0), 15) * TILW + min(max(u, 0), 30);

    const float* pin = inp + (size_t)b * (CIN * H_ * W_);

    // ---- staging chunk geometry: C = j*256+t, 16B chunks, 1024/group ----
    int soff[4];   // global dword offset within a channel-group
    int lofs[4];   // LDS dword offset (padded)
    #pragma unroll
    for (int j = 0; j < 4; ++j) {
        int C   = j * 256 + t;
        int chl = C >> 7;              // 0..7
        int rem = C & 127;
        int row = rem >> 3;            // 0..15
        int c4  = rem & 7;             // 0..7 (4-dword col group)
        soff[j] = (chl << 12) + (ry_lo + row) * W_ + cx_lo + (c4 << 2);
        lofs[j] = chl * (16 * TILW) + row * TILW + (c4 << 2);
    }

    // MFMA identity
    const int lane = t & 63;
    const int wv   = t >> 6;
    const int quad = lane >> 4;
    const int mrow = lane & 15;        // == pix
    const int q8   = quad << 3;
    const __hip_bfloat16* Arow0 = A + ((size_t)(wv * 32 + mrow) << 11);
    const __hip_bfloat16* Arow1 = Arow0 + (16 << 11);
    const int brot = mrow << 3;

    f32x4 acc0 = {0.f, 0.f, 0.f, 0.f};
    f32x4 acc1 = {0.f, 0.f, 0.f, 0.f};

    // ---- preload group 0 ----
    f32x4u pf[4];
    #pragma unroll
    for (int j = 0; j < 4; ++j)
        pf[j] = *(const f32x4u*)(const void*)(pin + soff[j]);
    #pragma unroll
    for (int j = 0; j < 4; ++j)
        *(f32x4u*)(void*)(tile + lofs[j]) = pf[j];
    __syncthreads();

    #pragma unroll 1
    for (int q = 0; q < 4; ++q) {
        #pragma unroll 1
        for (int gi = 0; gi < 4; ++gi) {
            const int gidx  = (q << 2) + gi;       // current group in tile
            const int gn    = (gidx + 1) & 15;     // prefetch target
            const int cbase = gidx << 3;

            // prefetch next group into registers (overlaps gather)
            #pragma unroll
            for (int j = 0; j < 4; ++j)
                pf[j] = *(const f32x4u*)(const void*)(pin + (gn << 15) + soff[j]);

            // gather 8 channels from padded tile -> Bs quarter
            #pragma unroll 4
            for (int c8 = 0; c8 < 8; ++c8) {
                const float* tb = tile + c8 * (16 * TILW);
                f32x2u f0 = *(const f32x2u*)(const void*)(tb + tc0);
                f32x2u f1 = *(const f32x2u*)(const void*)(tb + tc1);
                float s = l00 * f0[0] + l01 * f0[1] + l10 * f1[0] + l11 * f1[1];
                if (!intile) {         // exec-skipped ~always; exact tail
                    const float* p = pin + ((size_t)(cbase + c8) << 12);
                    f32x2u h0 = *(const f32x2u*)(const void*)(p + ad0);
                    f32x2u h1 = *(const f32x2u*)(const void*)(p + ad1);
                    s += b00 * h0[0] + b01 * h0[1] + b10 * h1[0] + b11 * h1[1];
                }
                int kkl = (((cbase + c8) & 31) << 4) + k;
                Bs[(pix << 9) + ((kkl + (pix << 3)) & (KKQ - 1))] = __float2bfloat16(s);
            }
            __syncthreads();           // tile reads + Bs writes done

            // write prefetched group into tile
            #pragma unroll
            for (int j = 0; j < 4; ++j)
                *(f32x4u*)(void*)(tile + lofs[j]) = pf[j];
            __syncthreads();           // tile writes visible
        }

        // ---- MFMA over this quarter's 512 kk ----
        const __hip_bfloat16* Aq0 = Arow0 + (q << 9);
        const __hip_bfloat16* Aq1 = Arow1 + (q << 9);
        const __hip_bfloat16* bsb = &Bs[mrow << 9];
        #pragma unroll 4
        for (int it = 0; it < 16; ++it) {
            int kk0 = (it << 5) + q8;
            bf16x8 av0 = *(const bf16x8*)(const void*)(Aq0 + kk0);
            bf16x8 av1 = *(const bf16x8*)(const void*)(Aq1 + kk0);
            bf16x8 bb  = *(const bf16x8*)(const void*)(bsb + ((kk0 + brot) & (KKQ - 1)));
            acc0 = __builtin_amdgcn_mfma_f32_16x16x32_bf16(av0, bb, acc0, 0, 0, 0);
            acc1 = __builtin_amdgcn_mfma_f32_16x16x32_bf16(av1, bb, acc1, 0, 0, 0);
        }
        __syncthreads();               // Bs reads done before next quarter's writes
    }

    // ---- epilogue: C/D col=lane&15 (pixel), row=quad*4+j (cout) ----
    if (pvalid) {
        size_t outb = (size_t)b * (COUT * HW_) + r;
        #pragma unroll
        for (int j = 0; j < 4; ++j) {
            int o = wv * 32 + quad * 4 + j;
            out[outb + (size_t)o        * HW_] = acc0[j] + bias[o];
            out[outb + (size_t)(o + 16) * HW_] = acc1[j] + bias[o + 16];
        }
    }
}

extern "C" void kernel_launch(void* const* d_in, const int* in_sizes, int n_in,
                              void* d_out, int out_size, void* d_ws, size_t ws_size,
                              hipStream_t stream) {
    const float* inp  = (const float*)d_in[0];
    const float* off  = (const float*)d_in[1];
    const float* msk  = (const float*)d_in[2];
    const float* wgt  = (const float*)d_in[3];
    const float* bias = (const float*)d_in[4];
    float* out = (float*)d_out;

    __hip_bfloat16* A = (__hip_bfloat16*)d_ws;   // 512 KB

    prep_weight<<<(COUT * KKTOT) / 256, 256, 0, stream>>>(wgt, A);

    int nblk = B_ * HO * 4;            // 1952 (bid&7 = batch)
    deform_main<<<nblk, 256, 0, stream>>>(inp, off, msk, A, bias, out);
}

// Round 5
// 216.488 us; speedup vs baseline: 1.8053x; 1.0093x over previous
//
#include <hip/hip_runtime.h>
#include <hip/hip_bf16.h>

// Problem constants
#define B_    8
#define CIN   128
#define H_    64
#define W_    64
#define COUT  128
#define K_    16
#define HO    61
#define WO    61
#define HW_   (HO * WO)          // 3721
#define KKTOT (CIN * K_)         // 2048
#define KKQ   512                // kk per quarter (Bs = 16 KB)
#define TILW  40                 // tile row stride (words): bank = (8*row+col)%32
#define TILCH 8                  // channels per tile group
#define TILSZ (TILCH * 16 * TILW) // 5120 floats = 20.5 KB

typedef short bf16x8 __attribute__((ext_vector_type(8)));
typedef float f32x4  __attribute__((ext_vector_type(4)));
typedef float f32x2u __attribute__((ext_vector_type(2), aligned(4)));
typedef float f32x4u __attribute__((ext_vector_type(4), aligned(4)));

// Pre-flip weight (transposed-conv: k' = 15-k), bf16.  A[o][c*16+k] = w[o][c][15-k]
__global__ __launch_bounds__(256) void prep_weight(const float* __restrict__ w,
                                                   __hip_bfloat16* __restrict__ A) {
    int idx = blockIdx.x * 256 + threadIdx.x;
    int o   = idx >> 11;
    int rem = idx & 2047;
    int c   = rem >> 4;
    int k   = rem & 15;
    A[idx]  = __float2bfloat16(w[(o << 11) + (c << 4) + (15 - k)]);
}

// Block = 16 pixels of one (b,ho) row segment x 128 couts. 256 thr = (pix, tap).
// LDS tile (row stride 40 words -> 8-bank/row rotation kills gather conflicts)
// per 8-channel group, staged via coalesced global->VGPR->ds_write with register
// prefetch; bilinear gather from LDS; Bs quarter (512 kk) feeds MFMA.
// 36.9 KB LDS -> 4 blocks/CU.
__global__ __launch_bounds__(256, 4) void deform_main(
        const float* __restrict__ inp, const float* __restrict__ off,
        const float* __restrict__ msk, const __hip_bfloat16* __restrict__ A,
        const float* __restrict__ bias, float* __restrict__ out) {

    __shared__ __align__(16) __hip_bfloat16 Bs[16 * KKQ];   // 16 KB
    __shared__ __align__(16) float tile[TILSZ];             // 20.5 KB

    const int t   = threadIdx.x;
    const int pix = t & 15;
    const int k   = t >> 4;            // tap 0..15

    // ---- block decode: bid&7 = batch (XCD/L2 pinning) ----
    const int bid = blockIdx.x;
    const int b   = bid & 7;
    const int g   = bid >> 3;
    const int ho  = g >> 2;
    const int wt  = (g & 3) << 4;
    const int wo  = wt + pix;
    const bool pvalid = (wo < WO);
    const int wo_c = pvalid ? wo : (WO - 1);
    const int r    = ho * WO + wo_c;

    // ---- window: 16 rows x 32 cols, margin ~6 sigma; cx 4-aligned ----
    const int ry_lo = min(max(ho - 6, 0), H_ - 16);
    const int cx_lo = min(max(wt - 6, 0), W_ - 32) & ~3;

    // ---- per-(pixel,tap) sampling params ----
    const int ki = k >> 2, kj = k & 3;
    const size_t offb = (size_t)b * (2 * K_ * HW_);
    float dy = off[offb + (size_t)(2 * k)     * HW_ + r];
    float dx = off[offb + (size_t)(2 * k + 1) * HW_ + r];
    float mm = msk[(size_t)b * (K_ * HW_) + (size_t)k * HW_ + r];
    if (!pvalid) mm = 0.0f;

    float y   = dy + (float)(ki + ho);
    float x   = dx + (float)(kj + wo_c);
    float y0f = floorf(y), x0f = floorf(x);
    float wy  = y - y0f,   wx  = x - x0f;
    int y0 = (int)y0f, x0 = (int)x0f;
    int y1 = y0 + 1,   x1 = x0 + 1;

    float wy0v = (1.0f - wy) * ((y0 >= 0 && y0 < H_) ? mm : 0.0f);
    float wy1v = wy          * ((y1 >= 0 && y1 < H_) ? mm : 0.0f);
    int cy0 = min(max(y0, 0), H_ - 1), cy1 = min(max(y1, 0), H_ - 1);

    float wx0v = (1.0f - wx) * ((x0 >= 0 && x0 < W_) ? 1.0f : 0.0f);
    float wx1v = wx          * ((x1 >= 0 && x1 < W_) ? 1.0f : 0.0f);
    int xb = min(max(x0, 0), W_ - 2);
    int tsh = x0 - xb;                 // -1,0,1 (else both x-weights are 0)
    float a0 = (tsh == 0) ? wx0v : ((tsh == -1) ? wx1v : 0.0f);
    float a1 = (tsh == 0) ? wx1v : ((tsh ==  1) ? wx0v : 0.0f);

    const float b00 = wy0v * a0, b01 = wy0v * a1;
    const float b10 = wy1v * a0, b11 = wy1v * a1;
    const int ad0 = cy0 * W_ + xb;     // exact global fallback addrs
    const int ad1 = cy1 * W_ + xb;

    // tile coords + in-window test (fallback handles the ~6-sigma tail exactly)
    int t0 = cy0 - ry_lo, t1 = cy1 - ry_lo, u = xb - cx_lo;
    const bool intile = (t0 >= 0) & (t0 < 16) & (t1 >= 0) & (t1 < 16) &
                        (u >= 0) & (u <= 30);
    const float l00 = intile ? b00 : 0.0f, l01 = intile ? b01 : 0.0f;
    const float l10 = intile ? b10 : 0.0f, l11 = intile ? b11 : 0.0f;
    const int tc0 = min(max(t0, 0), 15) * TILW + min(max(u, 0), 30);
    const int tc1 = min(max(t1, 0), 15) * TILW + min(max(u, 0), 30);

    const float* pin = inp + (size_t)b * (CIN * H_ * W_);

    // ---- staging chunk geometry: C = j*256+t, 16B chunks, 1024/group ----
    int soff[4];   // global dword offset within a channel-group
    int lofs[4];   // LDS dword offset (stride-40 rows)
    #pragma unroll
    for (int j = 0; j < 4; ++j) {
        int C   = j * 256 + t;
        int chl = C >> 7;              // 0..7
        int rem = C & 127;
        int row = rem >> 3;            // 0..15
        int c4  = rem & 7;             // 0..7 (4-dword col group)
        soff[j] = (chl << 12) + (ry_lo + row) * W_ + cx_lo + (c4 << 2);
        lofs[j] = chl * (16 * TILW) + row * TILW + (c4 << 2);
    }

    // MFMA identity
    const int lane = t & 63;
    const int wv   = t >> 6;
    const int quad = lane >> 4;
    const int mrow = lane & 15;        // == pix
    const int q8   = quad << 3;
    const __hip_bfloat16* Arow0 = A + ((size_t)(wv * 32 + mrow) << 11);
    const __hip_bfloat16* Arow1 = Arow0 + (16 << 11);
    const int brot = mrow << 3;

    f32x4 acc0 = {0.f, 0.f, 0.f, 0.f};
    f32x4 acc1 = {0.f, 0.f, 0.f, 0.f};

    // ---- preload group 0 ----
    f32x4u pf[4];
    #pragma unroll
    for (int j = 0; j < 4; ++j)
        pf[j] = *(const f32x4u*)(const void*)(pin + soff[j]);
    #pragma unroll
    for (int j = 0; j < 4; ++j)
        *(f32x4u*)(void*)(tile + lofs[j]) = pf[j];
    __syncthreads();

    #pragma unroll 1
    for (int q = 0; q < 4; ++q) {
        #pragma unroll 1
        for (int gi = 0; gi < 4; ++gi) {
            const int gidx  = (q << 2) + gi;       // current group in tile
            const int gn    = (gidx + 1) & 15;     // prefetch target
            const int cbase = gidx << 3;

            // prefetch next group into registers (overlaps gather)
            #pragma unroll
            for (int j = 0; j < 4; ++j)
                pf[j] = *(const f32x4u*)(const void*)(pin + (gn << 15) + soff[j]);

            // gather 8 channels from tile -> Bs quarter (fully unrolled:
            // batches the ds_reads so residual conflicts overlap)
            #pragma unroll
            for (int c8 = 0; c8 < 8; ++c8) {
                const float* tb = tile + c8 * (16 * TILW);
                f32x2u f0 = *(const f32x2u*)(const void*)(tb + tc0);
                f32x2u f1 = *(const f32x2u*)(const void*)(tb + tc1);
                float s = l00 * f0[0] + l01 * f0[1] + l10 * f1[0] + l11 * f1[1];
                if (!intile) {         // exec-skipped ~always; exact tail
                    const float* p = pin + ((size_t)(cbase + c8) << 12);
                    f32x2u h0 = *(const f32x2u*)(const void*)(p + ad0);
                    f32x2u h1 = *(const f32x2u*)(const void*)(p + ad1);
                    s += b00 * h0[0] + b01 * h0[1] + b10 * h1[0] + b11 * h1[1];
                }
                int kkl = (((cbase + c8) & 31) << 4) + k;
                Bs[(pix << 9) + ((kkl + (pix << 3)) & (KKQ - 1))] = __float2bfloat16(s);
            }
            __syncthreads();           // tile reads + Bs writes done

            // write prefetched group into tile
            #pragma unroll
            for (int j = 0; j < 4; ++j)
                *(f32x4u*)(void*)(tile + lofs[j]) = pf[j];
            __syncthreads();           // tile writes visible
        }

        // ---- MFMA over this quarter's 512 kk ----
        const __hip_bfloat16* Aq0 = Arow0 + (q << 9);
        const __hip_bfloat16* Aq1 = Arow1 + (q << 9);
        const __hip_bfloat16* bsb = &Bs[mrow << 9];
        #pragma unroll 4
        for (int it = 0; it < 16; ++it) {
            int kk0 = (it << 5) + q8;
            bf16x8 av0 = *(const bf16x8*)(const void*)(Aq0 + kk0);
            bf16x8 av1 = *(const bf16x8*)(const void*)(Aq1 + kk0);
            bf16x8 bb  = *(const bf16x8*)(const void*)(bsb + ((kk0 + brot) & (KKQ - 1)));
            acc0 = __builtin_amdgcn_mfma_f32_16x16x32_bf16(av0, bb, acc0, 0, 0, 0);
            acc1 = __builtin_amdgcn_mfma_f32_16x16x32_bf16(av1, bb, acc1, 0, 0, 0);
        }
        __syncthreads();               // Bs reads done before next quarter's writes
    }

    // ---- epilogue: C/D col=lane&15 (pixel), row=quad*4+j (cout) ----
    if (pvalid) {
        size_t outb = (size_t)b * (COUT * HW_) + r;
        #pragma unroll
        for (int j = 0; j < 4; ++j) {
            int o = wv * 32 + quad * 4 + j;
            out[outb + (size_t)o        * HW_] = acc0[j] + bias[o];
            out[outb + (size_t)(o + 16) * HW_] = acc1[j] + bias[o + 16];
        }
    }
}

extern "C" void kernel_launch(void* const* d_in, const int* in_sizes, int n_in,
                              void* d_out, int out_size, void* d_ws, size_t ws_size,
                              hipStream_t stream) {
    const float* inp  = (const float*)d_in[0];
    const float* off  = (const float*)d_in[1];
    const float* msk  = (const float*)d_in[2];
    const float* wgt  = (const float*)d_in[3];
    const float* bias = (const float*)d_in[4];
    float* out = (float*)d_out;

    __hip_bfloat16* A = (__hip_bfloat16*)d_ws;   // 512 KB

    prep_weight<<<(COUT * KKTOT) / 256, 256, 0, stream>>>(wgt, A);

    int nblk = B_ * HO * 4;            // 1952 (bid&7 = batch)
    deform_main<<<nblk, 256, 0, stream>>>(inp, off, msk, A, bias, out);
}

// Round 6
// 215.453 us; speedup vs baseline: 1.8140x; 1.0048x over previous
//
#include <hip/hip_runtime.h>
#include <hip/hip_bf16.h>

// Problem constants
#define B_    8
#define CIN   128
#define H_    64
#define W_    64
#define COUT  128
#define K_    16
#define HO    61
#define WO    61
#define HW_   (HO * WO)          // 3721
#define KKTOT (CIN * K_)         // 2048
#define KKQ   512                // kk per quarter (Bs = 16 KB)
#define TILW  40                 // tile row stride (words): bank = (8*row+col)%32
#define TILCH 4                  // channels per tile group
#define TILSZ (TILCH * 16 * TILW) // 2560 floats = 10.25 KB

typedef short bf16x8 __attribute__((ext_vector_type(8)));
typedef float f32x4  __attribute__((ext_vector_type(4)));
typedef float f32x2u __attribute__((ext_vector_type(2), aligned(4)));
typedef float f32x4u __attribute__((ext_vector_type(4), aligned(4)));

// Pre-flip weight (transposed-conv: k' = 15-k), bf16.  A[o][c*16+k] = w[o][c][15-k]
__global__ __launch_bounds__(256) void prep_weight(const float* __restrict__ w,
                                                   __hip_bfloat16* __restrict__ A) {
    int idx = blockIdx.x * 256 + threadIdx.x;
    int o   = idx >> 11;
    int rem = idx & 2047;
    int c   = rem >> 4;
    int k   = rem & 15;
    A[idx]  = __float2bfloat16(w[(o << 11) + (c << 4) + (15 - k)]);
}

// Block = 16 pixels of one (b,ho) row segment x 128 couts. 256 thr = (pix, tap).
// 4-channel LDS tile groups (10.25 KB) + Bs quarter (16 KB) = 26.25 KB LDS
// -> 6 blocks/CU (24 waves, 75% occ) to cover LDS/barrier latency.
__global__ __launch_bounds__(256, 6) void deform_main(
        const float* __restrict__ inp, const float* __restrict__ off,
        const float* __restrict__ msk, const __hip_bfloat16* __restrict__ A,
        const float* __restrict__ bias, float* __restrict__ out) {

    __shared__ __align__(16) __hip_bfloat16 Bs[16 * KKQ];   // 16 KB
    __shared__ __align__(16) float tile[TILSZ];             // 10.25 KB

    const int t   = threadIdx.x;
    const int pix = t & 15;
    const int k   = t >> 4;            // tap 0..15

    // ---- block decode: bid&7 = batch (XCD/L2 pinning) ----
    const int bid = blockIdx.x;
    const int b   = bid & 7;
    const int g   = bid >> 3;
    const int ho  = g >> 2;
    const int wt  = (g & 3) << 4;
    const int wo  = wt + pix;
    const bool pvalid = (wo < WO);
    const int wo_c = pvalid ? wo : (WO - 1);
    const int r    = ho * WO + wo_c;

    // ---- window: 16 rows x 32 cols, margin ~6 sigma; cx 4-aligned ----
    const int ry_lo = min(max(ho - 6, 0), H_ - 16);
    const int cx_lo = min(max(wt - 6, 0), W_ - 32) & ~3;

    // ---- per-(pixel,tap) sampling params ----
    const int ki = k >> 2, kj = k & 3;
    const size_t offb = (size_t)b * (2 * K_ * HW_);
    float dy = off[offb + (size_t)(2 * k)     * HW_ + r];
    float dx = off[offb + (size_t)(2 * k + 1) * HW_ + r];
    float mm = msk[(size_t)b * (K_ * HW_) + (size_t)k * HW_ + r];
    if (!pvalid) mm = 0.0f;

    float y   = dy + (float)(ki + ho);
    float x   = dx + (float)(kj + wo_c);
    float y0f = floorf(y), x0f = floorf(x);
    float wy  = y - y0f,   wx  = x - x0f;
    int y0 = (int)y0f, x0 = (int)x0f;
    int y1 = y0 + 1,   x1 = x0 + 1;

    float wy0v = (1.0f - wy) * ((y0 >= 0 && y0 < H_) ? mm : 0.0f);
    float wy1v = wy          * ((y1 >= 0 && y1 < H_) ? mm : 0.0f);
    int cy0 = min(max(y0, 0), H_ - 1), cy1 = min(max(y1, 0), H_ - 1);

    float wx0v = (1.0f - wx) * ((x0 >= 0 && x0 < W_) ? 1.0f : 0.0f);
    float wx1v = wx          * ((x1 >= 0 && x1 < W_) ? 1.0f : 0.0f);
    int xb = min(max(x0, 0), W_ - 2);
    int tsh = x0 - xb;                 // -1,0,1 (else both x-weights are 0)
    float a0 = (tsh == 0) ? wx0v : ((tsh == -1) ? wx1v : 0.0f);
    float a1 = (tsh == 0) ? wx1v : ((tsh ==  1) ? wx0v : 0.0f);

    const float b00 = wy0v * a0, b01 = wy0v * a1;
    const float b10 = wy1v * a0, b11 = wy1v * a1;
    const int ad0 = cy0 * W_ + xb;     // exact global fallback addrs
    const int ad1 = cy1 * W_ + xb;

    // tile coords + in-window test (fallback handles the ~6-sigma tail exactly)
    int t0 = cy0 - ry_lo, t1 = cy1 - ry_lo, u = xb - cx_lo;
    const bool intile = (t0 >= 0) & (t0 < 16) & (t1 >= 0) & (t1 < 16) &
                        (u >= 0) & (u <= 30);
    const float l00 = intile ? b00 : 0.0f, l01 = intile ? b01 : 0.0f;
    const float l10 = intile ? b10 : 0.0f, l11 = intile ? b11 : 0.0f;
    const int tc0 = min(max(t0, 0), 15) * TILW + min(max(u, 0), 30);
    const int tc1 = min(max(t1, 0), 15) * TILW + min(max(u, 0), 30);

    const float* pin = inp + (size_t)b * (CIN * H_ * W_);

    // ---- staging chunk geometry: C = j*256+t, 16B chunks, 512/group ----
    int soff[2];   // global dword offset within a 4-channel group
    int lofs[2];   // LDS dword offset (stride-40 rows)
    #pragma unroll
    for (int j = 0; j < 2; ++j) {
        int C   = j * 256 + t;
        int chl = C >> 7;              // 0..3
        int rem = C & 127;
        int row = rem >> 3;            // 0..15
        int c4  = rem & 7;             // 0..7 (4-dword col group)
        soff[j] = (chl << 12) + (ry_lo + row) * W_ + cx_lo + (c4 << 2);
        lofs[j] = chl * (16 * TILW) + row * TILW + (c4 << 2);
    }

    // MFMA identity
    const int lane = t & 63;
    const int wv   = t >> 6;
    const int quad = lane >> 4;
    const int mrow = lane & 15;        // == pix
    const int q8   = quad << 3;
    const __hip_bfloat16* Arow0 = A + ((size_t)(wv * 32 + mrow) << 11);
    const __hip_bfloat16* Arow1 = Arow0 + (16 << 11);
    const int brot = mrow << 3;

    f32x4 acc0 = {0.f, 0.f, 0.f, 0.f};
    f32x4 acc1 = {0.f, 0.f, 0.f, 0.f};

    // ---- preload group 0 (channels 0..3) ----
    f32x4u pf[2];
    #pragma unroll
    for (int j = 0; j < 2; ++j)
        pf[j] = *(const f32x4u*)(const void*)(pin + soff[j]);
    #pragma unroll
    for (int j = 0; j < 2; ++j)
        *(f32x4u*)(void*)(tile + lofs[j]) = pf[j];
    __syncthreads();

    #pragma unroll 1
    for (int q = 0; q < 4; ++q) {
        #pragma unroll 1
        for (int gi = 0; gi < 8; ++gi) {
            const int gidx  = (q << 3) + gi;       // current 4-ch group
            const int gn    = (gidx + 1) & 31;     // prefetch target
            const int cbase = gidx << 2;

            // prefetch next group into registers (overlaps gather)
            #pragma unroll
            for (int j = 0; j < 2; ++j)
                pf[j] = *(const f32x4u*)(const void*)(pin + (gn << 14) + soff[j]);

            // gather 4 channels from tile -> Bs quarter
            #pragma unroll
            for (int c4 = 0; c4 < 4; ++c4) {
                const float* tb = tile + c4 * (16 * TILW);
                f32x2u f0 = *(const f32x2u*)(const void*)(tb + tc0);
                f32x2u f1 = *(const f32x2u*)(const void*)(tb + tc1);
                float s = l00 * f0[0] + l01 * f0[1] + l10 * f1[0] + l11 * f1[1];
                if (!intile) {         // exec-skipped ~always; exact tail
                    const float* p = pin + ((size_t)(cbase + c4) << 12);
                    f32x2u h0 = *(const f32x2u*)(const void*)(p + ad0);
                    f32x2u h1 = *(const f32x2u*)(const void*)(p + ad1);
                    s += b00 * h0[0] + b01 * h0[1] + b10 * h1[0] + b11 * h1[1];
                }
                int kkl = (((cbase + c4) & 31) << 4) + k;
                Bs[(pix << 9) + ((kkl + (pix << 3)) & (KKQ - 1))] = __float2bfloat16(s);
            }
            __syncthreads();           // tile reads + Bs writes done

            // write prefetched group into tile
            #pragma unroll
            for (int j = 0; j < 2; ++j)
                *(f32x4u*)(void*)(tile + lofs[j]) = pf[j];
            __syncthreads();           // tile writes visible
        }

        // ---- MFMA over this quarter's 512 kk ----
        const __hip_bfloat16* Aq0 = Arow0 + (q << 9);
        const __hip_bfloat16* Aq1 = Arow1 + (q << 9);
        const __hip_bfloat16* bsb = &Bs[mrow << 9];
        #pragma unroll 4
        for (int it = 0; it < 16; ++it) {
            int kk0 = (it << 5) + q8;
            bf16x8 av0 = *(const bf16x8*)(const void*)(Aq0 + kk0);
            bf16x8 av1 = *(const bf16x8*)(const void*)(Aq1 + kk0);
            bf16x8 bb  = *(const bf16x8*)(const void*)(bsb + ((kk0 + brot) & (KKQ - 1)));
            acc0 = __builtin_amdgcn_mfma_f32_16x16x32_bf16(av0, bb, acc0, 0, 0, 0);
            acc1 = __builtin_amdgcn_mfma_f32_16x16x32_bf16(av1, bb, acc1, 0, 0, 0);
        }
        __syncthreads();               // Bs reads done before next quarter's writes
    }

    // ---- epilogue: C/D col=lane&15 (pixel), row=quad*4+j (cout) ----
    if (pvalid) {
        size_t outb = (size_t)b * (COUT * HW_) + r;
        #pragma unroll
        for (int j = 0; j < 4; ++j) {
            int o = wv * 32 + quad * 4 + j;
            out[outb + (size_t)o        * HW_] = acc0[j] + bias[o];
            out[outb + (size_t)(o + 16) * HW_] = acc1[j] + bias[o + 16];
        }
    }
}

extern "C" void kernel_launch(void* const* d_in, const int* in_sizes, int n_in,
                              void* d_out, int out_size, void* d_ws, size_t ws_size,
                              hipStream_t stream) {
    const float* inp  = (const float*)d_in[0];
    const float* off  = (const float*)d_in[1];
    const float* msk  = (const float*)d_in[2];
    const float* wgt  = (const float*)d_in[3];
    const float* bias = (const float*)d_in[4];
    float* out = (float*)d_out;

    __hip_bfloat16* A = (__hip_bfloat16*)d_ws;   // 512 KB

    prep_weight<<<(COUT * KKTOT) / 256, 256, 0, stream>>>(wgt, A);

    int nblk = B_ * HO * 4;            // 1952 (bid&7 = batch)
    deform_main<<<nblk, 256, 0, stream>>>(inp, off, msk, A, bias, out);
}